// Round 3
// baseline (556.777 us; speedup 1.0000x reference)
//
#include <hip/hip_runtime.h>
#include <hip/hip_bf16.h>

#define NB 8
#define NN 256
#define NL 32
#define NQ 8192              // NN*NL
#define NH 64
#define SL ((size_t)NQ * NN) // 2097152 elements per (b,k) T1 slab

typedef __attribute__((ext_vector_type(8))) short short8v;
typedef __attribute__((ext_vector_type(4))) float float4v;
typedef __attribute__((ext_vector_type(16))) float float16v;

static __device__ __forceinline__ ushort f2bf(float f) {
  __hip_bfloat16 h = __float2bfloat16(f);
  return *reinterpret_cast<const ushort*>(&h);
}
static __device__ __forceinline__ uint packbf(float a, float b) {
  return (uint)f2bf(a) | ((uint)f2bf(b) << 16);
}

// ---------------------------------------------------------------------------
// Gt[k][m][n] = bf16(G[k][n][m])
// ---------------------------------------------------------------------------
__global__ __launch_bounds__(256) void prep_g(const float* __restrict__ G,
                                              ushort* __restrict__ Gt) {
  __shared__ float t[32][33];
  const int k = blockIdx.z, m0 = blockIdx.x * 32, n0 = blockIdx.y * 32;
  const int tid = threadIdx.x;
  const int c = tid & 31, r8 = tid >> 5;
#pragma unroll
  for (int i = 0; i < 4; ++i) {
    int r = r8 + i * 8;
    t[r][c] = G[((size_t)k * NN + n0 + r) * NN + m0 + c];
  }
  __syncthreads();
#pragma unroll
  for (int i = 0; i < 4; ++i) {
    int rm = r8 + i * 8;
    Gt[((size_t)k * NN + m0 + rm) * NN + n0 + c] = f2bf(t[c][rm]);
  }
}

// ---------------------------------------------------------------------------
// Wt[h][kjl] = bf16(W[kjl][h])   (64 x 288)
// ---------------------------------------------------------------------------
__global__ __launch_bounds__(256) void prep_w(const float* __restrict__ W,
                                              ushort* __restrict__ Wt) {
  const int tid = threadIdx.x;
#pragma unroll
  for (int i = 0; i < 18; ++i) {
    int g = i * 256 + tid;
    int r = g >> 4;
    int h4 = (g & 15) * 4;
    float4 w = *(const float4*)(W + (size_t)r * NH + h4);
    Wt[(size_t)(h4 + 0) * 288 + r] = f2bf(w.x);
    Wt[(size_t)(h4 + 1) * 288 + r] = f2bf(w.y);
    Wt[(size_t)(h4 + 2) * 288 + r] = f2bf(w.z);
    Wt[(size_t)(h4 + 3) * 288 + r] = f2bf(w.w);
  }
}

// ---------------------------------------------------------------------------
// Xt[b][q'][n] = bf16(X[b][n][q]),  q = c*32+l,  q' = l*256+c
// ---------------------------------------------------------------------------
__global__ __launch_bounds__(256) void prep_x(const float* __restrict__ X,
                                              ushort* __restrict__ Xt) {
  __shared__ float t[32][33];
  const int qt = blockIdx.x;
  const int n0 = blockIdx.y * 32;
  const int b  = blockIdx.z;
  const int tid = threadIdx.x;
  const int c = tid & 31, r8 = tid >> 5;
  const float* Xb = X + (size_t)b * NN * NQ;
  ushort* Xo = Xt + (size_t)b * SL;
  const size_t q0 = (size_t)qt * 32;
#pragma unroll
  for (int i = 0; i < 4; ++i) {
    int r = r8 + i * 8;
    t[r][c] = Xb[(size_t)(n0 + r) * NQ + q0 + c];
  }
  __syncthreads();
#pragma unroll
  for (int i = 0; i < 4; ++i) {
    int l = r8 + i * 8;
    Xo[((size_t)l * NN + qt) * NN + n0 + c] = f2bf(t[c][l]);
  }
}

// ---------------------------------------------------------------------------
// Stage 1 GEMM: C[M][N] = A[M][K] * Bt[N][K]^T  (bf16, fp32 acc, 128x128 tile)
// z: A += (z%3)*aMs ; Bt += (z/3)*bDs ; C += z*cs
// ---------------------------------------------------------------------------
__global__ __launch_bounds__(256) void gemm_bt(
    const ushort* __restrict__ A, const ushort* __restrict__ Bt,
    ushort* __restrict__ C, int N, int K,
    size_t aMs, size_t bDs, size_t cs) {
  __shared__ short As[128][40];
  __shared__ short Bs[128][40];
  const int z = blockIdx.z;
  A  += (size_t)(z % 3) * aMs;
  Bt += (size_t)(z / 3) * bDs;
  C  += (size_t)z * cs;
  const int n0 = blockIdx.x * 128;
  const int m0 = blockIdx.y * 128;
  const int tid = threadIdx.x;
  const int lane = tid & 63;
  const int w = tid >> 6;
  const int wr = (w >> 1) * 64, wc = (w & 1) * 64;
  const int sr = tid >> 1, sc = (tid & 1) * 16;
  const int fr = lane & 15, fg = (lane >> 4) * 8;

  float4v acc[4][4] = {};

  const ushort* ap = A + (size_t)(m0 + sr) * K + sc;
  const ushort* bp = Bt + (size_t)(n0 + sr) * K + sc;

  for (int kk = 0; kk < K; kk += 32) {
    *(float4*)&As[sr][sc]     = *(const float4*)(ap + kk);
    *(float4*)&As[sr][sc + 8] = *(const float4*)(ap + kk + 8);
    *(float4*)&Bs[sr][sc]     = *(const float4*)(bp + kk);
    *(float4*)&Bs[sr][sc + 8] = *(const float4*)(bp + kk + 8);
    __syncthreads();
    short8v af[4], bf[4];
#pragma unroll
    for (int i = 0; i < 4; ++i)
      af[i] = *(const short8v*)&As[wr + i * 16 + fr][fg];
#pragma unroll
    for (int j = 0; j < 4; ++j)
      bf[j] = *(const short8v*)&Bs[wc + j * 16 + fr][fg];
#pragma unroll
    for (int i = 0; i < 4; ++i)
#pragma unroll
      for (int j = 0; j < 4; ++j)
        acc[i][j] = __builtin_amdgcn_mfma_f32_16x16x32_bf16(af[i], bf[j],
                                                            acc[i][j], 0, 0, 0);
    __syncthreads();
  }

  const int rbase = (lane >> 4) * 4;
#pragma unroll
  for (int i = 0; i < 4; ++i) {
    const int row = m0 + wr + i * 16 + rbase;
#pragma unroll
    for (int j = 0; j < 4; ++j) {
      const int col = n0 + wc + j * 16 + fr;
      ushort* cp = C + (size_t)row * N + col;
#pragma unroll
      for (int r = 0; r < 4; ++r)
        cp[(size_t)r * N] = f2bf(acc[i][j][r]);
    }
  }
}

// ---------------------------------------------------------------------------
// Fused stage 2+3. Block: (b, m-pair, 64-d tile). 4 waves (2 m x 2 d-halves).
// k outer, j inner (Gt re-reads are L2-hot; T1 staged 3x only).
// Stage2: C2[l 32][d 32] per wave via mfma_32x32x16 from swizzled LDS tiles.
// In-register transpose (pack + shfl_xor 32) -> stage3 B operand.
// Stage3: out^T[h][d] += Wt-frag x B, acc over all 9 (k,j). Bias+ReLU store.
// LDS granule swizzle: 16B granule g of row r lives at g ^ (r & 31).
// ---------------------------------------------------------------------------
#define LDSOFF(row, gc) ((((row) << 5) + (((gc) ^ ((row) & 31)))) << 3)

__global__ __launch_bounds__(256, 2) void fused_s23(
    const ushort* __restrict__ T1, const ushort* __restrict__ Gt,
    const ushort* __restrict__ Wt, const float* __restrict__ bias,
    float* __restrict__ out) {
  __shared__ short T1s[64 * 256];
  __shared__ short Gts[64 * 256];

  const int tid = threadIdx.x;
  const int d0 = blockIdx.x * 64;
  const int mp = blockIdx.y;
  const int b  = blockIdx.z;

  const int lane = tid & 63;
  const int w  = tid >> 6;
  const int l5 = lane & 31;
  const int h5 = lane >> 5;
  const int wi = (w >> 1) * 32;   // stage2 row block (mlocal*32)
  const int wj = (w & 1) * 32;    // stage2 col block (d within tile)

  const ushort* t1b = T1 + ((size_t)b * 3) * SL + (size_t)mp * 64 * 256;
  const ushort* gtb = Gt + (size_t)d0 * NN;

  float4 rT[8], rG[8];

  auto issueT1 = [&](int k) {
    const ushort* s = t1b + (size_t)k * SL;
#pragma unroll
    for (int i = 0; i < 8; ++i) {
      int gf = tid + i * 256;
      rT[i] = *(const float4*)(s + ((gf >> 5) << 8) + ((gf & 31) << 3));
    }
  };
  auto issueG = [&](int j) {
    const ushort* s = gtb + (size_t)j * NN * NN;
#pragma unroll
    for (int i = 0; i < 8; ++i) {
      int gf = tid + i * 256;
      rG[i] = *(const float4*)(s + ((gf >> 5) << 8) + ((gf & 31) << 3));
    }
  };
  auto writeT1 = [&]() {
#pragma unroll
    for (int i = 0; i < 8; ++i) {
      int gf = tid + i * 256;
      *(float4*)&T1s[LDSOFF(gf >> 5, gf & 31)] = rT[i];
    }
  };
  auto writeG = [&]() {
#pragma unroll
    for (int i = 0; i < 8; ++i) {
      int gf = tid + i * 256;
      *(float4*)&Gts[LDSOFF(gf >> 5, gf & 31)] = rG[i];
    }
  };

  float16v acc3[2] = {};

  // prologue: stage (k=0, j=0)
  issueT1(0);
  issueG(0);
  writeT1();
  writeG();

  const int arow = wi + l5;
  const int brow = wj + l5;

  for (int t = 0; t < 9; ++t) {
    const int kj = t;             // k = t/3, j = t%3 -> kj index = k*3+j = t
    __syncthreads();              // staged tiles visible

    const int tn = t + 1;
    const bool doG = (tn < 9);
    const bool doT = (tn < 9) && (tn % 3 == 0);
    if (doG) issueG(tn % 3);
    if (doT) issueT1(tn / 3);

    // ---- stage 2: 16 K-steps of 32x32x16
    float16v acc2 = {};
#pragma unroll
    for (int ks = 0; ks < 16; ++ks) {
      short8v av = *(const short8v*)&T1s[LDSOFF(arow, 2 * ks + h5)];
      short8v bv = *(const short8v*)&Gts[LDSOFF(brow, 2 * ks + h5)];
      acc2 = __builtin_amdgcn_mfma_f32_32x32x16_bf16(av, bv, acc2, 0, 0, 0);
    }
    __syncthreads();              // all stage2 reads done -> LDS reusable

    // ---- in-register transpose: C2(l,d) -> stage3 B operand (k=l, col=d)
    uint P[8], Xc[8];
#pragma unroll
    for (int q = 0; q < 8; ++q) P[q] = packbf(acc2[2 * q], acc2[2 * q + 1]);
#pragma unroll
    for (int q = 0; q < 8; ++q) Xc[q] = (uint)__shfl_xor((int)P[q], 32);

    short8v Bf[2];
#pragma unroll
    for (int kp = 0; kp < 2; ++kp) {
      uint4 u;
      if (h5 == 0) {
        u.x = P[4 * kp];     u.y = P[4 * kp + 1];
        u.z = Xc[4 * kp];    u.w = Xc[4 * kp + 1];
      } else {
        u.x = Xc[4 * kp + 2]; u.y = Xc[4 * kp + 3];
        u.z = P[4 * kp + 2];  u.w = P[4 * kp + 3];
      }
      Bf[kp] = *(short8v*)&u;
    }

    // ---- stage 3: out^T[h][d] accumulate; A-frags from L2-hot Wt
#pragma unroll
    for (int hb = 0; hb < 2; ++hb) {
#pragma unroll
      for (int kp = 0; kp < 2; ++kp) {
        short8v Af = *(const short8v*)(Wt + (size_t)(hb * 32 + l5) * 288 +
                                       kj * 32 + kp * 16 + h5 * 8);
        acc3[hb] = __builtin_amdgcn_mfma_f32_32x32x16_bf16(Af, Bf[kp],
                                                           acc3[hb], 0, 0, 0);
      }
    }

    // ---- write next staged tiles (overlaps with other waves' stage3)
    if (doG) writeG();
    if (doT) writeT1();
  }

  // ---- epilogue: bias + ReLU, out[b][m][d][h]
  const int m = mp * 2 + (w >> 1);
  const int d = d0 + wj + l5;
  float* ob = out + (((size_t)b * NN + m) * NN + d) * NH;
#pragma unroll
  for (int hb = 0; hb < 2; ++hb) {
#pragma unroll
    for (int s = 0; s < 4; ++s) {
      const int h = hb * 32 + s * 8 + h5 * 4;
      const float4 bb = *(const float4*)(bias + h);
      float4 v;
      v.x = fmaxf(acc3[hb][4 * s + 0] + bb.x, 0.f);
      v.y = fmaxf(acc3[hb][4 * s + 1] + bb.y, 0.f);
      v.z = fmaxf(acc3[hb][4 * s + 2] + bb.z, 0.f);
      v.w = fmaxf(acc3[hb][4 * s + 3] + bb.w, 0.f);
      *(float4*)(ob + h) = v;
    }
  }
}

extern "C" void kernel_launch(void* const* d_in, const int* in_sizes, int n_in,
                              void* d_out, int out_size, void* d_ws, size_t ws_size,
                              hipStream_t stream) {
  (void)in_sizes; (void)n_in; (void)out_size; (void)ws_size;
  const float* X    = (const float*)d_in[0];
  const float* G    = (const float*)d_in[1];
  const float* W    = (const float*)d_in[2];
  const float* bias = (const float*)d_in[3];
  float* out = (float*)d_out;

  char* p = (char*)d_ws;
  ushort* Gt = (ushort*)p;  p += (size_t)3 * NN * NN * 2;   // 384 KB
  ushort* Wt = (ushort*)p;  p += (size_t)NH * 288 * 2;      // 36 KB
  ushort* Xt = (ushort*)p;  p += (size_t)NB * SL * 2;       // 33.5 MB
  ushort* T1 = (ushort*)p;                                  // 100.7 MB (24 slabs)

  prep_g<<<dim3(8, 8, 3), 256, 0, stream>>>(G, Gt);
  prep_w<<<dim3(1), 256, 0, stream>>>(W, Wt);
  prep_x<<<dim3(256, 8, NB), 256, 0, stream>>>(X, Xt);

  // Stage 1 for all (b,k): z = b*3+k ; A = Gt[k], Bt = Xt[b], C = T1[z]
  gemm_bt<<<dim3(NQ / 128, NN / 128, 24), 256, 0, stream>>>(
      Gt, Xt, T1, NQ, NN, (size_t)NN * NN, SL, SL);

  // Fused stage 2+3 for all b
  fused_s23<<<dim3(4, 128, NB), 256, 0, stream>>>(T1, Gt, Wt, bias, out);
}

// Round 4
// 544.651 us; speedup vs baseline: 1.0223x; 1.0223x over previous
//
#include <hip/hip_runtime.h>
#include <hip/hip_bf16.h>

#define NB 8
#define NN 256
#define NL 32
#define NQ 8192              // NN*NL
#define NH 64
#define SL ((size_t)NQ * NN) // 2097152 elements per (b,k) T1 slab

typedef __attribute__((ext_vector_type(8))) short short8v;
typedef __attribute__((ext_vector_type(4))) float float4v;
typedef __attribute__((ext_vector_type(16))) float float16v;

static __device__ __forceinline__ ushort f2bf(float f) {
  __hip_bfloat16 h = __float2bfloat16(f);
  return *reinterpret_cast<const ushort*>(&h);
}
static __device__ __forceinline__ uint packbf(float a, float b) {
  return (uint)f2bf(a) | ((uint)f2bf(b) << 16);
}

// ---------------------------------------------------------------------------
// Gt[k][m][n] = bf16(G[k][n][m])
// ---------------------------------------------------------------------------
__global__ __launch_bounds__(256) void prep_g(const float* __restrict__ G,
                                              ushort* __restrict__ Gt) {
  __shared__ float t[32][33];
  const int k = blockIdx.z, m0 = blockIdx.x * 32, n0 = blockIdx.y * 32;
  const int tid = threadIdx.x;
  const int c = tid & 31, r8 = tid >> 5;
#pragma unroll
  for (int i = 0; i < 4; ++i) {
    int r = r8 + i * 8;
    t[r][c] = G[((size_t)k * NN + n0 + r) * NN + m0 + c];
  }
  __syncthreads();
#pragma unroll
  for (int i = 0; i < 4; ++i) {
    int rm = r8 + i * 8;
    Gt[((size_t)k * NN + m0 + rm) * NN + n0 + c] = f2bf(t[c][rm]);
  }
}

// ---------------------------------------------------------------------------
// Wt[h][kjl] = bf16(W[kjl][h])   (64 x 288)
// ---------------------------------------------------------------------------
__global__ __launch_bounds__(256) void prep_w(const float* __restrict__ W,
                                              ushort* __restrict__ Wt) {
  const int tid = threadIdx.x;
#pragma unroll
  for (int i = 0; i < 18; ++i) {
    int g = i * 256 + tid;
    int r = g >> 4;
    int h4 = (g & 15) * 4;
    float4 w = *(const float4*)(W + (size_t)r * NH + h4);
    Wt[(size_t)(h4 + 0) * 288 + r] = f2bf(w.x);
    Wt[(size_t)(h4 + 1) * 288 + r] = f2bf(w.y);
    Wt[(size_t)(h4 + 2) * 288 + r] = f2bf(w.z);
    Wt[(size_t)(h4 + 3) * 288 + r] = f2bf(w.w);
  }
}

// ---------------------------------------------------------------------------
// Xt[b][q'][n] = bf16(X[b][n][q]),  q = c*32+l,  q' = l*256+c
// ---------------------------------------------------------------------------
__global__ __launch_bounds__(256) void prep_x(const float* __restrict__ X,
                                              ushort* __restrict__ Xt) {
  __shared__ float t[32][33];
  const int qt = blockIdx.x;
  const int n0 = blockIdx.y * 32;
  const int b  = blockIdx.z;
  const int tid = threadIdx.x;
  const int c = tid & 31, r8 = tid >> 5;
  const float* Xb = X + (size_t)b * NN * NQ;
  ushort* Xo = Xt + (size_t)b * SL;
  const size_t q0 = (size_t)qt * 32;
#pragma unroll
  for (int i = 0; i < 4; ++i) {
    int r = r8 + i * 8;
    t[r][c] = Xb[(size_t)(n0 + r) * NQ + q0 + c];
  }
  __syncthreads();
#pragma unroll
  for (int i = 0; i < 4; ++i) {
    int l = r8 + i * 8;
    Xo[((size_t)l * NN + qt) * NN + n0 + c] = f2bf(t[c][l]);
  }
}

// ---------------------------------------------------------------------------
// Stage 1 GEMM: C[M][N] = A[M][K] * Bt[N][K]^T  (bf16, fp32 acc, 128x128 tile)
// z: A += (z%3)*aMs ; Bt += (z/3)*bDs ; C += z*cs
// ---------------------------------------------------------------------------
__global__ __launch_bounds__(256) void gemm_bt(
    const ushort* __restrict__ A, const ushort* __restrict__ Bt,
    ushort* __restrict__ C, int N, int K,
    size_t aMs, size_t bDs, size_t cs) {
  __shared__ short As[128][40];
  __shared__ short Bs[128][40];
  const int z = blockIdx.z;
  A  += (size_t)(z % 3) * aMs;
  Bt += (size_t)(z / 3) * bDs;
  C  += (size_t)z * cs;
  const int n0 = blockIdx.x * 128;
  const int m0 = blockIdx.y * 128;
  const int tid = threadIdx.x;
  const int lane = tid & 63;
  const int w = tid >> 6;
  const int wr = (w >> 1) * 64, wc = (w & 1) * 64;
  const int sr = tid >> 1, sc = (tid & 1) * 16;
  const int fr = lane & 15, fg = (lane >> 4) * 8;

  float4v acc[4][4] = {};

  const ushort* ap = A + (size_t)(m0 + sr) * K + sc;
  const ushort* bp = Bt + (size_t)(n0 + sr) * K + sc;

  for (int kk = 0; kk < K; kk += 32) {
    *(float4*)&As[sr][sc]     = *(const float4*)(ap + kk);
    *(float4*)&As[sr][sc + 8] = *(const float4*)(ap + kk + 8);
    *(float4*)&Bs[sr][sc]     = *(const float4*)(bp + kk);
    *(float4*)&Bs[sr][sc + 8] = *(const float4*)(bp + kk + 8);
    __syncthreads();
    short8v af[4], bf[4];
#pragma unroll
    for (int i = 0; i < 4; ++i)
      af[i] = *(const short8v*)&As[wr + i * 16 + fr][fg];
#pragma unroll
    for (int j = 0; j < 4; ++j)
      bf[j] = *(const short8v*)&Bs[wc + j * 16 + fr][fg];
#pragma unroll
    for (int i = 0; i < 4; ++i)
#pragma unroll
      for (int j = 0; j < 4; ++j)
        acc[i][j] = __builtin_amdgcn_mfma_f32_16x16x32_bf16(af[i], bf[j],
                                                            acc[i][j], 0, 0, 0);
    __syncthreads();
  }

  const int rbase = (lane >> 4) * 4;
#pragma unroll
  for (int i = 0; i < 4; ++i) {
    const int row = m0 + wr + i * 16 + rbase;
#pragma unroll
    for (int j = 0; j < 4; ++j) {
      const int col = n0 + wc + j * 16 + fr;
      ushort* cp = C + (size_t)row * N + col;
#pragma unroll
      for (int r = 0; r < 4; ++r)
        cp[(size_t)r * N] = f2bf(acc[i][j][r]);
    }
  }
}

// ---------------------------------------------------------------------------
// Fused stage 2+3. Logical block (b, m-pair, 64-d tile); 1D grid with
// XCD-aware swizzle so the 4 d-tiles sharing one T1 tile run on ONE XCD
// (T1 fetched from HBM once, then L2-hit). 4 waves (2 m x 2 d-halves).
// Stage2: C2[l 32][d 32] per wave via mfma_32x32x16 from swizzled LDS tiles.
// In-register transpose (pack + shfl_xor 32) -> stage3 B operand.
// Stage3: out^T[h][d] += Wt-frag x B over 9 (k,j). Epilogue stages through
// LDS (fp32 [m][d][h], pad 68) so global stores are full-line coalesced.
// LDS granule swizzle for bf16 tiles: 16B granule g of row r at g ^ (r & 31).
// ---------------------------------------------------------------------------
#define LDSOFF(row, gc) ((((row) << 5) + (((gc) ^ ((row) & 31)))) << 3)

__global__ __launch_bounds__(256, 2) void fused_s23(
    const ushort* __restrict__ T1, const ushort* __restrict__ Gt,
    const ushort* __restrict__ Wt, const float* __restrict__ bias,
    float* __restrict__ out) {
  __shared__ short SMEM[2 * 64 * 256];       // 64 KB, reused by epilogue
  short* T1s = SMEM;
  short* Gts = SMEM + 64 * 256;

  const int tid = threadIdx.x;
  // XCD swizzle: hw id f -> logical lid; consecutive lids share an XCD chunk.
  const int f = blockIdx.x;
  const int lid = (f & 7) * 512 + (f >> 3);
  const int d0 = (lid & 3) * 64;
  const int mp = (lid >> 2) & 127;
  const int b  = lid >> 9;

  const int lane = tid & 63;
  const int w  = tid >> 6;
  const int l5 = lane & 31;
  const int h5 = lane >> 5;
  const int wi = (w >> 1) * 32;   // stage2 row block ((m-local)*32)
  const int wj = (w & 1) * 32;    // stage2 col block (d within tile)

  const ushort* t1b = T1 + ((size_t)b * 3) * SL + (size_t)mp * 64 * 256;
  const ushort* gtb = Gt + (size_t)d0 * NN;

  float4 rT[8], rG[8];

  auto issueT1 = [&](int k) {
    const ushort* s = t1b + (size_t)k * SL;
#pragma unroll
    for (int i = 0; i < 8; ++i) {
      int gf = tid + i * 256;
      rT[i] = *(const float4*)(s + ((gf >> 5) << 8) + ((gf & 31) << 3));
    }
  };
  auto issueG = [&](int j) {
    const ushort* s = gtb + (size_t)j * NN * NN;
#pragma unroll
    for (int i = 0; i < 8; ++i) {
      int gf = tid + i * 256;
      rG[i] = *(const float4*)(s + ((gf >> 5) << 8) + ((gf & 31) << 3));
    }
  };
  auto writeT1 = [&]() {
#pragma unroll
    for (int i = 0; i < 8; ++i) {
      int gf = tid + i * 256;
      *(float4*)&T1s[LDSOFF(gf >> 5, gf & 31)] = rT[i];
    }
  };
  auto writeG = [&]() {
#pragma unroll
    for (int i = 0; i < 8; ++i) {
      int gf = tid + i * 256;
      *(float4*)&Gts[LDSOFF(gf >> 5, gf & 31)] = rG[i];
    }
  };

  float16v acc3[2] = {};

  // prologue: stage (k=0, j=0)
  issueT1(0);
  issueG(0);
  writeT1();
  writeG();

  const int arow = wi + l5;
  const int brow = wj + l5;

  for (int t = 0; t < 9; ++t) {
    const int kj = t;             // k = t/3, j = t%3
    __syncthreads();              // staged tiles visible

    const int tn = t + 1;
    const bool doG = (tn < 9);
    const bool doT = (tn < 9) && (tn % 3 == 0);
    if (doG) issueG(tn % 3);
    if (doT) issueT1(tn / 3);

    // ---- stage 2: 16 K-steps of 32x32x16
    float16v acc2 = {};
#pragma unroll
    for (int ks = 0; ks < 16; ++ks) {
      short8v av = *(const short8v*)&T1s[LDSOFF(arow, 2 * ks + h5)];
      short8v bv = *(const short8v*)&Gts[LDSOFF(brow, 2 * ks + h5)];
      acc2 = __builtin_amdgcn_mfma_f32_32x32x16_bf16(av, bv, acc2, 0, 0, 0);
    }
    __syncthreads();              // all stage2 reads done -> LDS reusable

    // ---- in-register transpose: C2(l,d) -> stage3 B operand (k=l, col=d)
    uint P[8], Xc[8];
#pragma unroll
    for (int q = 0; q < 8; ++q) P[q] = packbf(acc2[2 * q], acc2[2 * q + 1]);
#pragma unroll
    for (int q = 0; q < 8; ++q) Xc[q] = (uint)__shfl_xor((int)P[q], 32);

    short8v Bf[2];
#pragma unroll
    for (int kp = 0; kp < 2; ++kp) {
      uint4 u;
      if (h5 == 0) {
        u.x = P[4 * kp];     u.y = P[4 * kp + 1];
        u.z = Xc[4 * kp];    u.w = Xc[4 * kp + 1];
      } else {
        u.x = Xc[4 * kp + 2]; u.y = Xc[4 * kp + 3];
        u.z = P[4 * kp + 2];  u.w = P[4 * kp + 3];
      }
      Bf[kp] = *(short8v*)&u;
    }

    // ---- stage 3: out^T[h][d] accumulate; A-frags from L2-hot Wt
#pragma unroll
    for (int hb = 0; hb < 2; ++hb) {
#pragma unroll
      for (int kp = 0; kp < 2; ++kp) {
        short8v Af = *(const short8v*)(Wt + (size_t)(hb * 32 + l5) * 288 +
                                       kj * 32 + kp * 16 + h5 * 8);
        acc3[hb] = __builtin_amdgcn_mfma_f32_32x32x16_bf16(Af, Bf[kp],
                                                           acc3[hb], 0, 0, 0);
      }
    }

    // ---- write next staged tiles (overlaps with other waves' stage3)
    if (doG) writeG();
    if (doT) writeT1();
  }

  // ---- epilogue: stage fp32 [m-local][d][h] in LDS (pad 68), then
  //      fully-coalesced contiguous stores with bias+ReLU.
  float* epi = (float*)SMEM;                 // 2*64*68 floats = 34.8 KB
  {
    const int ml = w >> 1;
    float* ep = epi + ((size_t)(ml * 64 + wj + l5)) * 68;
#pragma unroll
    for (int hb = 0; hb < 2; ++hb) {
#pragma unroll
      for (int s = 0; s < 4; ++s) {
        float4 v;
        v.x = acc3[hb][4 * s + 0];
        v.y = acc3[hb][4 * s + 1];
        v.z = acc3[hb][4 * s + 2];
        v.w = acc3[hb][4 * s + 3];
        *(float4*)(ep + hb * 32 + s * 8 + h5 * 4) = v;
      }
    }
  }
  __syncthreads();
#pragma unroll
  for (int ml2 = 0; ml2 < 2; ++ml2) {
    float* ob = out + (((size_t)b * NN + mp * 2 + ml2) * NN + d0) * NH;
#pragma unroll
    for (int p = 0; p < 4; ++p) {
      const int idx = p * 1024 + tid * 4;    // contiguous over [d][h]
      const int dd = idx >> 6, h = idx & 63;
      float4 v = *(float4*)(epi + (size_t)(ml2 * 64 + dd) * 68 + h);
      const float4 bb = *(const float4*)(bias + h);
      v.x = fmaxf(v.x + bb.x, 0.f);
      v.y = fmaxf(v.y + bb.y, 0.f);
      v.z = fmaxf(v.z + bb.z, 0.f);
      v.w = fmaxf(v.w + bb.w, 0.f);
      *(float4*)(ob + idx) = v;
    }
  }
}

extern "C" void kernel_launch(void* const* d_in, const int* in_sizes, int n_in,
                              void* d_out, int out_size, void* d_ws, size_t ws_size,
                              hipStream_t stream) {
  (void)in_sizes; (void)n_in; (void)out_size; (void)ws_size;
  const float* X    = (const float*)d_in[0];
  const float* G    = (const float*)d_in[1];
  const float* W    = (const float*)d_in[2];
  const float* bias = (const float*)d_in[3];
  float* out = (float*)d_out;

  char* p = (char*)d_ws;
  ushort* Gt = (ushort*)p;  p += (size_t)3 * NN * NN * 2;   // 384 KB
  ushort* Wt = (ushort*)p;  p += (size_t)NH * 288 * 2;      // 36 KB
  ushort* Xt = (ushort*)p;  p += (size_t)NB * SL * 2;       // 33.5 MB
  ushort* T1 = (ushort*)p;                                  // 100.7 MB (24 slabs)

  prep_g<<<dim3(8, 8, 3), 256, 0, stream>>>(G, Gt);
  prep_w<<<dim3(1), 256, 0, stream>>>(W, Wt);
  prep_x<<<dim3(256, 8, NB), 256, 0, stream>>>(X, Xt);

  // Stage 1 for all (b,k): z = b*3+k ; A = Gt[k], Bt = Xt[b], C = T1[z]
  gemm_bt<<<dim3(NQ / 128, NN / 128, 24), 256, 0, stream>>>(
      Gt, Xt, T1, NQ, NN, (size_t)NN * NN, SL, SL);

  // Fused stage 2+3 for all b (4096 logical blocks, XCD-swizzled 1D grid)
  fused_s23<<<dim3(4096), 256, 0, stream>>>(T1, Gt, Wt, bias, out);
}

// Round 5
// 258.147 us; speedup vs baseline: 2.1568x; 2.1099x over previous
//
#include <hip/hip_runtime.h>
#include <hip/hip_bf16.h>

#define NB 8
#define NN 256
#define NL 32
#define NQ 8192              // NN*NL
#define NH 64
#define SL ((size_t)NQ * NN) // elements per (b,k) T1 slab

typedef __attribute__((ext_vector_type(8))) short short8v;
typedef __attribute__((ext_vector_type(4))) float float4v;
typedef __attribute__((ext_vector_type(16))) float float16v;

static __device__ __forceinline__ ushort f2bf(float f) {
  __hip_bfloat16 h = __float2bfloat16(f);
  return *reinterpret_cast<const ushort*>(&h);
}
static __device__ __forceinline__ uint packbf(float a, float b) {
  return (uint)f2bf(a) | ((uint)f2bf(b) << 16);
}
static __device__ __forceinline__ void gld_lds16(const void* g, void* l) {
  __builtin_amdgcn_global_load_lds(
      (const __attribute__((address_space(1))) unsigned int*)g,
      (__attribute__((address_space(3))) unsigned int*)l, 16, 0, 0);
}

// ---------------------------------------------------------------------------
// Gt[k][m][n] = bf16(G[k][n][m])
// ---------------------------------------------------------------------------
__global__ __launch_bounds__(256) void prep_g(const float* __restrict__ G,
                                              ushort* __restrict__ Gt) {
  __shared__ float t[32][33];
  const int k = blockIdx.z, m0 = blockIdx.x * 32, n0 = blockIdx.y * 32;
  const int tid = threadIdx.x;
  const int c = tid & 31, r8 = tid >> 5;
#pragma unroll
  for (int i = 0; i < 4; ++i) {
    int r = r8 + i * 8;
    t[r][c] = G[((size_t)k * NN + n0 + r) * NN + m0 + c];
  }
  __syncthreads();
#pragma unroll
  for (int i = 0; i < 4; ++i) {
    int rm = r8 + i * 8;
    Gt[((size_t)k * NN + m0 + rm) * NN + n0 + c] = f2bf(t[c][rm]);
  }
}

// ---------------------------------------------------------------------------
// WtF: stage-3 A fragments in lane order. Entry e = ((kj*2+kp)*2+hb)*64+lane,
// 16B granule = 8 bf16 of W rows (kj*32+kp*16+(lane>>5)*8 + 0..7), col h.
// ---------------------------------------------------------------------------
__global__ __launch_bounds__(256) void prep_wf(const float* __restrict__ W,
                                               ushort* __restrict__ WtF) {
  const int tid = threadIdx.x;
  for (int e = tid; e < 9 * 2 * 2 * 64; e += 256) {
    const int ln = e & 63, hb = (e >> 6) & 1, kp = (e >> 7) & 1, kj = e >> 8;
    const int h = hb * 32 + (ln & 31);
    const int c0 = kj * 32 + kp * 16 + (ln >> 5) * 8;
    ushort v[8];
#pragma unroll
    for (int i = 0; i < 8; ++i) v[i] = f2bf(W[(size_t)(c0 + i) * NH + h]);
    *(ulong2*)(WtF + (size_t)e * 8) = *(ulong2*)v;
  }
}

// ---------------------------------------------------------------------------
// Xt[b][q'][n] = bf16(X[b][n][q]),  q = c*32+l,  q' = l*256+c
// ---------------------------------------------------------------------------
__global__ __launch_bounds__(256) void prep_x(const float* __restrict__ X,
                                              ushort* __restrict__ Xt) {
  __shared__ float t[32][33];
  const int qt = blockIdx.x;
  const int n0 = blockIdx.y * 32;
  const int b  = blockIdx.z;
  const int tid = threadIdx.x;
  const int c = tid & 31, r8 = tid >> 5;
  const float* Xb = X + (size_t)b * NN * NQ;
  ushort* Xo = Xt + (size_t)b * SL;
  const size_t q0 = (size_t)qt * 32;
#pragma unroll
  for (int i = 0; i < 4; ++i) {
    int r = r8 + i * 8;
    t[r][c] = Xb[(size_t)(n0 + r) * NQ + q0 + c];
  }
  __syncthreads();
#pragma unroll
  for (int i = 0; i < 4; ++i) {
    int l = r8 + i * 8;
    Xo[((size_t)l * NN + qt) * NN + n0 + c] = f2bf(t[c][l]);
  }
}

// ---------------------------------------------------------------------------
// Stage 1 GEMM: C[M][N] = A[M][K] * Bt[N][K]^T  (bf16, fp32 acc, 128x128 tile)
// ---------------------------------------------------------------------------
__global__ __launch_bounds__(256) void gemm_bt(
    const ushort* __restrict__ A, const ushort* __restrict__ Bt,
    ushort* __restrict__ C, int N, int K,
    size_t aMs, size_t bDs, size_t cs) {
  __shared__ short As[128][40];
  __shared__ short Bs[128][40];
  const int z = blockIdx.z;
  A  += (size_t)(z % 3) * aMs;
  Bt += (size_t)(z / 3) * bDs;
  C  += (size_t)z * cs;
  const int n0 = blockIdx.x * 128;
  const int m0 = blockIdx.y * 128;
  const int tid = threadIdx.x;
  const int lane = tid & 63;
  const int w = tid >> 6;
  const int wr = (w >> 1) * 64, wc = (w & 1) * 64;
  const int sr = tid >> 1, sc = (tid & 1) * 16;
  const int fr = lane & 15, fg = (lane >> 4) * 8;

  float4v acc[4][4] = {};

  const ushort* ap = A + (size_t)(m0 + sr) * K + sc;
  const ushort* bp = Bt + (size_t)(n0 + sr) * K + sc;

  for (int kk = 0; kk < K; kk += 32) {
    *(float4*)&As[sr][sc]     = *(const float4*)(ap + kk);
    *(float4*)&As[sr][sc + 8] = *(const float4*)(ap + kk + 8);
    *(float4*)&Bs[sr][sc]     = *(const float4*)(bp + kk);
    *(float4*)&Bs[sr][sc + 8] = *(const float4*)(bp + kk + 8);
    __syncthreads();
    short8v af[4], bf[4];
#pragma unroll
    for (int i = 0; i < 4; ++i)
      af[i] = *(const short8v*)&As[wr + i * 16 + fr][fg];
#pragma unroll
    for (int j = 0; j < 4; ++j)
      bf[j] = *(const short8v*)&Bs[wc + j * 16 + fr][fg];
#pragma unroll
    for (int i = 0; i < 4; ++i)
#pragma unroll
      for (int j = 0; j < 4; ++j)
        acc[i][j] = __builtin_amdgcn_mfma_f32_16x16x32_bf16(af[i], bf[j],
                                                            acc[i][j], 0, 0, 0);
    __syncthreads();
  }

  const int rbase = (lane >> 4) * 4;
#pragma unroll
  for (int i = 0; i < 4; ++i) {
    const int row = m0 + wr + i * 16 + rbase;
#pragma unroll
    for (int j = 0; j < 4; ++j) {
      const int col = n0 + wc + j * 16 + fr;
      ushort* cp = C + (size_t)row * N + col;
#pragma unroll
      for (int r = 0; r < 4; ++r)
        cp[(size_t)r * N] = f2bf(acc[i][j][r]);
    }
  }
}

// ---------------------------------------------------------------------------
// Fused stage 2+3 v2. Block tile: 128 ml-rows (4 m) x 128 d. 4 waves (2x2),
// wave tile 64x64 (2x2 of 32x32 MFMA -> 1.0 LDS reads/MFMA, 4 indep chains).
// K=256 staged in two 128-halves via global_load_lds (pre-swizzled source,
// XOR-granule LDS). Stage3 A-frags from fragment-packed WtF (coalesced).
// Epilogue: 2 passes of 2 m each staged in LDS, coalesced fp32 stores.
// ---------------------------------------------------------------------------
__global__ __launch_bounds__(256, 2) void fused_s23(
    const ushort* __restrict__ T1, const ushort* __restrict__ Gt,
    const ushort* __restrict__ WtF, const float* __restrict__ bias,
    float* __restrict__ out) {
  __shared__ ulong2 LDSQ[4096];              // 64 KB
  char* base = (char*)LDSQ;

  const int tid = threadIdx.x;
  const int f = blockIdx.x;                  // 1024 blocks
  const int lid = (f & 7) * 128 + (f >> 3);  // XCD-contiguous logical id
  const int dblk = lid & 1;
  const int mp   = (lid >> 1) & 63;
  const int b    = lid >> 7;

  const int lane = tid & 63;
  const int w  = tid >> 6;
  const int l5 = lane & 31;
  const int h5 = lane >> 5;
  const int wml = (w >> 1) * 64;             // wave ml-base in tile
  const int wd  = (w & 1) * 64;              // wave d-base in tile
  const int d0  = dblk * 128;

  const ushort* t1b = T1 + ((size_t)b * 3) * SL + (size_t)mp * 128 * 256;

  // LDS read helper: granule-swizzled b128
  auto ldv = [&](int buf, int row, int gq) -> short8v {
    return *(const short8v*)(base + buf + (((row << 4) + (gq ^ (row & 15))) << 4));
  };

  float16v acc3[2][2][2] = {};   // [msub][dsub][hb]

  for (int kj = 0; kj < 9; ++kj) {
    const int k = (kj >= 6) ? 2 : (kj >= 3 ? 1 : 0);
    const int j = kj - k * 3;
    const ushort* t1k = t1b + (size_t)k * SL;
    const ushort* gtj = Gt + (size_t)j * NN * NN + (size_t)d0 * NN;

    float16v acc2[2][2] = {};    // [msub][dsub]

    for (int ch = 0; ch < 2; ++ch) {
      __syncthreads();           // prior reads of LDS done
      // ---- stage T1 half + Gt half via global_load_lds (linear LDS dest,
      //      inverse-swizzled global source)
#pragma unroll
      for (int i = 0; i < 8; ++i) {
        const int gl = tid + i * 256;        // linear granule 0..2047
        const int row = gl >> 4;
        const int sg = (gl & 15) ^ (row & 15);
        char* dst = base + ((i * 256 + (tid & 192)) << 4);
        gld_lds16(t1k + (size_t)row * 256 + ch * 128 + sg * 8, dst);
      }
#pragma unroll
      for (int i = 0; i < 8; ++i) {
        const int gl = tid + i * 256;
        const int row = gl >> 4;
        const int sg = (gl & 15) ^ (row & 15);
        char* dst = base + 32768 + ((i * 256 + (tid & 192)) << 4);
        gld_lds16(gtj + (size_t)row * 256 + ch * 128 + sg * 8, dst);
      }
      __syncthreads();           // DMA drained (vmcnt(0) before barrier)

      // ---- compute half: 8 K-steps x 4 MFMA (shared af/bf)
#pragma unroll
      for (int ks = 0; ks < 8; ++ks) {
        const int gq = 2 * ks + h5;
        short8v af0 = ldv(0,     wml + l5,      gq);
        short8v af1 = ldv(0,     wml + 32 + l5, gq);
        short8v bf0 = ldv(32768, wd + l5,       gq);
        short8v bf1 = ldv(32768, wd + 32 + l5,  gq);
        acc2[0][0] = __builtin_amdgcn_mfma_f32_32x32x16_bf16(af0, bf0, acc2[0][0], 0, 0, 0);
        acc2[0][1] = __builtin_amdgcn_mfma_f32_32x32x16_bf16(af0, bf1, acc2[0][1], 0, 0, 0);
        acc2[1][0] = __builtin_amdgcn_mfma_f32_32x32x16_bf16(af1, bf0, acc2[1][0], 0, 0, 0);
        acc2[1][1] = __builtin_amdgcn_mfma_f32_32x32x16_bf16(af1, bf1, acc2[1][1], 0, 0, 0);
      }
    }

    // ---- stage3 A-frags (coalesced 1KB wave loads from L2-hot WtF)
    short8v Af[2][2];            // [kp][hb]
#pragma unroll
    for (int kp = 0; kp < 2; ++kp)
#pragma unroll
      for (int hb = 0; hb < 2; ++hb)
        Af[kp][hb] = *(const short8v*)(WtF +
            ((size_t)(((kj * 2 + kp) * 2 + hb) * 64 + lane)) * 8);

    // ---- per C2 tile: in-register transpose -> stage3 B operand -> 4 MFMA
#pragma unroll
    for (int ms = 0; ms < 2; ++ms) {
#pragma unroll
      for (int ds = 0; ds < 2; ++ds) {
        uint P[8], Xc[8];
#pragma unroll
        for (int q = 0; q < 8; ++q)
          P[q] = packbf(acc2[ms][ds][2 * q], acc2[ms][ds][2 * q + 1]);
#pragma unroll
        for (int q = 0; q < 8; ++q) Xc[q] = (uint)__shfl_xor((int)P[q], 32);
        short8v Bf[2];
#pragma unroll
        for (int kp = 0; kp < 2; ++kp) {
          uint4 u;
          if (h5 == 0) {
            u.x = P[4 * kp];      u.y = P[4 * kp + 1];
            u.z = Xc[4 * kp];     u.w = Xc[4 * kp + 1];
          } else {
            u.x = Xc[4 * kp + 2]; u.y = Xc[4 * kp + 3];
            u.z = P[4 * kp + 2];  u.w = P[4 * kp + 3];
          }
          Bf[kp] = *(short8v*)&u;
        }
#pragma unroll
        for (int hb = 0; hb < 2; ++hb) {
#pragma unroll
          for (int kp = 0; kp < 2; ++kp)
            acc3[ms][ds][hb] = __builtin_amdgcn_mfma_f32_32x32x16_bf16(
                Af[kp][hb], Bf[kp], acc3[ms][ds][hb], 0, 0, 0);
        }
      }
    }
  }

  // ---- epilogue: 2 passes of 2 m each; stage fp32 in swizzled LDS, then
  //      fully-coalesced stores with bias+ReLU.
  float4* EP = (float4*)base;    // [ml 2][d 128][hgran 16] float4 = 64 KB
#pragma unroll
  for (int mlp = 0; mlp < 2; ++mlp) {
    __syncthreads();             // LDS free / prior pass consumed
    if ((w >> 1) == mlp) {
#pragma unroll
      for (int ms = 0; ms < 2; ++ms) {
#pragma unroll
        for (int ds = 0; ds < 2; ++ds) {
          const int d = wd + ds * 32 + l5;
#pragma unroll
          for (int hb = 0; hb < 2; ++hb) {
#pragma unroll
            for (int s = 0; s < 4; ++s) {
              const int hg = 2 * s + h5 + 8 * hb;   // float4 granule of h
              float4 v;
              v.x = acc3[ms][ds][hb][4 * s + 0];
              v.y = acc3[ms][ds][hb][4 * s + 1];
              v.z = acc3[ms][ds][hb][4 * s + 2];
              v.w = acc3[ms][ds][hb][4 * s + 3];
              EP[(ms * 128 + d) * 16 + (hg ^ (d & 15))] = v;
            }
          }
        }
      }
    }
    __syncthreads();
    // coalesced store of 2 m rows (2 x 32 KB)
#pragma unroll
    for (int ii = 0; ii < 16; ++ii) {
      const int fi = tid + ii * 256;         // 0..4095 float4
      const int ml = fi >> 11;
      const int d  = (fi >> 4) & 127;
      const int hg = fi & 15;
      float4 v = EP[(ml * 128 + d) * 16 + (hg ^ (d & 15))];
      const float4 bb = *(const float4*)(bias + hg * 4);
      v.x = fmaxf(v.x + bb.x, 0.f);
      v.y = fmaxf(v.y + bb.y, 0.f);
      v.z = fmaxf(v.z + bb.z, 0.f);
      v.w = fmaxf(v.w + bb.w, 0.f);
      const int m = mp * 4 + mlp * 2 + ml;
      float* ob = out + (((size_t)b * NN + m) * NN + d0 + d) * NH;
      *(float4*)(ob + hg * 4) = v;
    }
  }
}

extern "C" void kernel_launch(void* const* d_in, const int* in_sizes, int n_in,
                              void* d_out, int out_size, void* d_ws, size_t ws_size,
                              hipStream_t stream) {
  (void)in_sizes; (void)n_in; (void)out_size; (void)ws_size;
  const float* X    = (const float*)d_in[0];
  const float* G    = (const float*)d_in[1];
  const float* W    = (const float*)d_in[2];
  const float* bias = (const float*)d_in[3];
  float* out = (float*)d_out;

  char* p = (char*)d_ws;
  ushort* Gt  = (ushort*)p;  p += (size_t)3 * NN * NN * 2;  // 384 KB
  ushort* WtF = (ushort*)p;  p += (size_t)64 * 1024;        // 36.9 KB (padded)
  ushort* Xt  = (ushort*)p;  p += (size_t)NB * SL * 2;      // 33.5 MB
  ushort* T1  = (ushort*)p;                                 // 100.7 MB

  prep_g<<<dim3(8, 8, 3), 256, 0, stream>>>(G, Gt);
  prep_wf<<<dim3(1), 256, 0, stream>>>(W, WtF);
  prep_x<<<dim3(256, 8, NB), 256, 0, stream>>>(X, Xt);

  // Stage 1 for all (b,k): z = b*3+k ; A = Gt[k], Bt = Xt[b], C = T1[z]
  gemm_bt<<<dim3(NQ / 128, NN / 128, 24), 256, 0, stream>>>(
      Gt, Xt, T1, NQ, NN, (size_t)NN * NN, SL, SL);

  // Fused stage 2+3 (1024 logical blocks, XCD-swizzled)
  fused_s23<<<dim3(1024), 256, 0, stream>>>(T1, Gt, WtF, bias, out);
}

// Round 6
// 209.422 us; speedup vs baseline: 2.6586x; 1.2327x over previous
//
#include <hip/hip_runtime.h>
#include <hip/hip_bf16.h>

#define NB 8
#define NN 256
#define NL 32
#define NQ 8192              // NN*NL
#define NH 64
#define SL ((size_t)NQ * NN) // elements per (b,k) T1 slab

typedef __attribute__((ext_vector_type(8))) short short8v;
typedef __attribute__((ext_vector_type(4))) float float4v;
typedef __attribute__((ext_vector_type(16))) float float16v;

static __device__ __forceinline__ ushort f2bf(float f) {
  __hip_bfloat16 h = __float2bfloat16(f);
  return *reinterpret_cast<const ushort*>(&h);
}
static __device__ __forceinline__ uint packbf(float a, float b) {
  return (uint)f2bf(a) | ((uint)f2bf(b) << 16);
}
static __device__ __forceinline__ void gld_lds16(const void* g, void* l) {
  __builtin_amdgcn_global_load_lds(
      (const __attribute__((address_space(1))) unsigned int*)g,
      (__attribute__((address_space(3))) unsigned int*)l, 16, 0, 0);
}

// ---------------------------------------------------------------------------
// Gt[k][m][n] = bf16(G[k][n][m])
// ---------------------------------------------------------------------------
__global__ __launch_bounds__(256) void prep_g(const float* __restrict__ G,
                                              ushort* __restrict__ Gt) {
  __shared__ float t[32][33];
  const int k = blockIdx.z, m0 = blockIdx.x * 32, n0 = blockIdx.y * 32;
  const int tid = threadIdx.x;
  const int c = tid & 31, r8 = tid >> 5;
#pragma unroll
  for (int i = 0; i < 4; ++i) {
    int r = r8 + i * 8;
    t[r][c] = G[((size_t)k * NN + n0 + r) * NN + m0 + c];
  }
  __syncthreads();
#pragma unroll
  for (int i = 0; i < 4; ++i) {
    int rm = r8 + i * 8;
    Gt[((size_t)k * NN + m0 + rm) * NN + n0 + c] = f2bf(t[c][rm]);
  }
}

// ---------------------------------------------------------------------------
// WtF: stage-3 A fragments in lane order. Entry e = ((kj*2+kp)*2+hb)*64+lane,
// 16B granule = 8 bf16 of W rows (kj*32+kp*16+(lane>>5)*8 + 0..7), col h.
// ---------------------------------------------------------------------------
__global__ __launch_bounds__(256) void prep_wf(const float* __restrict__ W,
                                               ushort* __restrict__ WtF) {
  const int tid = threadIdx.x;
  for (int e = tid; e < 9 * 2 * 2 * 64; e += 256) {
    const int ln = e & 63, hb = (e >> 6) & 1, kp = (e >> 7) & 1, kj = e >> 8;
    const int h = hb * 32 + (ln & 31);
    const int c0 = kj * 32 + kp * 16 + (ln >> 5) * 8;
    ushort v[8];
#pragma unroll
    for (int i = 0; i < 8; ++i) v[i] = f2bf(W[(size_t)(c0 + i) * NH + h]);
    *(ulong2*)(WtF + (size_t)e * 8) = *(ulong2*)v;
  }
}

// ---------------------------------------------------------------------------
// Xt[b][q'][n] = bf16(X[b][n][q]),  q = c*32+l,  q' = l*256+c
// ---------------------------------------------------------------------------
__global__ __launch_bounds__(256) void prep_x(const float* __restrict__ X,
                                              ushort* __restrict__ Xt) {
  __shared__ float t[32][33];
  const int qt = blockIdx.x;
  const int n0 = blockIdx.y * 32;
  const int b  = blockIdx.z;
  const int tid = threadIdx.x;
  const int c = tid & 31, r8 = tid >> 5;
  const float* Xb = X + (size_t)b * NN * NQ;
  ushort* Xo = Xt + (size_t)b * SL;
  const size_t q0 = (size_t)qt * 32;
#pragma unroll
  for (int i = 0; i < 4; ++i) {
    int r = r8 + i * 8;
    t[r][c] = Xb[(size_t)(n0 + r) * NQ + q0 + c];
  }
  __syncthreads();
#pragma unroll
  for (int i = 0; i < 4; ++i) {
    int l = r8 + i * 8;
    Xo[((size_t)l * NN + qt) * NN + n0 + c] = f2bf(t[c][l]);
  }
}

// ---------------------------------------------------------------------------
// Stage 1 GEMM: C[M][N] = A[M][K] * Bt[N][K]^T  (bf16, fp32 acc, 128x128 tile)
// ---------------------------------------------------------------------------
__global__ __launch_bounds__(256) void gemm_bt(
    const ushort* __restrict__ A, const ushort* __restrict__ Bt,
    ushort* __restrict__ C, int N, int K,
    size_t aMs, size_t bDs, size_t cs) {
  __shared__ short As[128][40];
  __shared__ short Bs[128][40];
  const int z = blockIdx.z;
  A  += (size_t)(z % 3) * aMs;
  Bt += (size_t)(z / 3) * bDs;
  C  += (size_t)z * cs;
  const int n0 = blockIdx.x * 128;
  const int m0 = blockIdx.y * 128;
  const int tid = threadIdx.x;
  const int lane = tid & 63;
  const int w = tid >> 6;
  const int wr = (w >> 1) * 64, wc = (w & 1) * 64;
  const int sr = tid >> 1, sc = (tid & 1) * 16;
  const int fr = lane & 15, fg = (lane >> 4) * 8;

  float4v acc[4][4] = {};

  const ushort* ap = A + (size_t)(m0 + sr) * K + sc;
  const ushort* bp = Bt + (size_t)(n0 + sr) * K + sc;

  for (int kk = 0; kk < K; kk += 32) {
    *(float4*)&As[sr][sc]     = *(const float4*)(ap + kk);
    *(float4*)&As[sr][sc + 8] = *(const float4*)(ap + kk + 8);
    *(float4*)&Bs[sr][sc]     = *(const float4*)(bp + kk);
    *(float4*)&Bs[sr][sc + 8] = *(const float4*)(bp + kk + 8);
    __syncthreads();
    short8v af[4], bf[4];
#pragma unroll
    for (int i = 0; i < 4; ++i)
      af[i] = *(const short8v*)&As[wr + i * 16 + fr][fg];
#pragma unroll
    for (int j = 0; j < 4; ++j)
      bf[j] = *(const short8v*)&Bs[wc + j * 16 + fr][fg];
#pragma unroll
    for (int i = 0; i < 4; ++i)
#pragma unroll
      for (int j = 0; j < 4; ++j)
        acc[i][j] = __builtin_amdgcn_mfma_f32_16x16x32_bf16(af[i], bf[j],
                                                            acc[i][j], 0, 0, 0);
    __syncthreads();
  }

  const int rbase = (lane >> 4) * 4;
#pragma unroll
  for (int i = 0; i < 4; ++i) {
    const int row = m0 + wr + i * 16 + rbase;
#pragma unroll
    for (int j = 0; j < 4; ++j) {
      const int col = n0 + wc + j * 16 + fr;
      ushort* cp = C + (size_t)row * N + col;
#pragma unroll
      for (int r = 0; r < 4; ++r)
        cp[(size_t)r * N] = f2bf(acc[i][j][r]);
    }
  }
}

// ---------------------------------------------------------------------------
// Fused stage 2+3 v3: software-pipelined quarter-K staging.
// Block tile 128 ml x 128 d, 4 waves (2x2), wave tile 64x64.
// 36 tiles = 9 (k,j) x 4 K-quarters (64 c). Ping-pong 32 KB buffers
// (T1-q 16 KB + Gt-q 16 KB each): per iter {sync; DMA(t+1 -> buf^1);
// compute(t <- buf)} so staging latency hides under LDS reads + MFMA.
// Stage3 (in-reg transpose + WtF MFMA) after each 4th quarter.
// ---------------------------------------------------------------------------
__global__ __launch_bounds__(256, 2) void fused_s23(
    const ushort* __restrict__ T1, const ushort* __restrict__ Gt,
    const ushort* __restrict__ WtF, const float* __restrict__ bias,
    float* __restrict__ out) {
  __shared__ ulong2 LDSQ[4096];              // 64 KB
  char* base = (char*)LDSQ;

  const int tid = threadIdx.x;
  const int f = blockIdx.x;                  // 1024 blocks
  const int lid = (f & 7) * 128 + (f >> 3);  // XCD-contiguous logical id
  const int dblk = lid & 1;
  const int mp   = (lid >> 1) & 63;
  const int b    = lid >> 7;

  const int lane = tid & 63;
  const int w  = tid >> 6;
  const int l5 = lane & 31;
  const int h5 = lane >> 5;
  const int wml = (w >> 1) * 64;             // wave ml-base in tile
  const int wd  = (w & 1) * 64;              // wave d-base in tile
  const int d0  = dblk * 128;

  const ushort* t1b  = T1 + ((size_t)b * 3) * SL + (size_t)mp * 128 * 256;
  const ushort* gtb0 = Gt + (size_t)d0 * NN;

  // DMA-stage tile t (= kj*4 + quarter) into buffer at byte offset qb.
  // Linear LDS dest (wave-uniform base + lane*16); inverse-swizzled source.
  auto stage = [&](int t, int qb) {
    const int kj = t >> 2, q = t & 3;
    const int k = (kj >= 6) ? 2 : (kj >= 3 ? 1 : 0);
    const int j = kj - k * 3;
    const ushort* t1k = t1b + (size_t)k * SL + q * 64;
    const ushort* gtj = gtb0 + (size_t)j * NN * NN + q * 64;
    char* d1 = base + qb + ((tid & 192) << 4);
    char* d2 = d1 + 16384;
#pragma unroll
    for (int i = 0; i < 4; ++i) {
      const int gl = i * 256 + tid;          // granule 0..1023
      const int row = gl >> 3;
      const int sg = (gl & 7) ^ (row & 7);
      gld_lds16(t1k + (size_t)row * 256 + sg * 8, d1 + (i << 12));
      gld_lds16(gtj + (size_t)row * 256 + sg * 8, d2 + (i << 12));
    }
  };
  // Swizzled b128 read from a staged tile (toff = 0 for T1, 16384 for Gt).
  auto ldv = [&](int qb, int toff, int row, int gq) -> short8v {
    return *(const short8v*)(base + qb + toff +
                             (((row << 3) + (gq ^ (row & 7))) << 4));
  };

  float16v acc3[2][2][2] = {};   // [msub][dsub][hb]
  float16v acc2[2][2] = {};      // [msub][dsub]

  stage(0, 0);                   // prologue

  for (int t = 0; t < 36; ++t) {
    const int qb = (t & 1) << 15;
    __syncthreads();             // tile t drained & visible; buf^1 reads done
    if (t + 1 < 36) stage(t + 1, qb ^ 32768);

    // ---- compute quarter: 4 K-steps x 4 MFMA (shared af/bf)
#pragma unroll
    for (int ks = 0; ks < 4; ++ks) {
      const int gq = 2 * ks + h5;
      short8v af0 = ldv(qb, 0,     wml + l5,      gq);
      short8v af1 = ldv(qb, 0,     wml + 32 + l5, gq);
      short8v bf0 = ldv(qb, 16384, wd + l5,       gq);
      short8v bf1 = ldv(qb, 16384, wd + 32 + l5,  gq);
      acc2[0][0] = __builtin_amdgcn_mfma_f32_32x32x16_bf16(af0, bf0, acc2[0][0], 0, 0, 0);
      acc2[0][1] = __builtin_amdgcn_mfma_f32_32x32x16_bf16(af0, bf1, acc2[0][1], 0, 0, 0);
      acc2[1][0] = __builtin_amdgcn_mfma_f32_32x32x16_bf16(af1, bf0, acc2[1][0], 0, 0, 0);
      acc2[1][1] = __builtin_amdgcn_mfma_f32_32x32x16_bf16(af1, bf1, acc2[1][1], 0, 0, 0);
    }

    if ((t & 3) == 3) {
      const int kj = t >> 2;
      // ---- stage3 A-frags (coalesced 1KB wave loads from L2-hot WtF)
      short8v Af[2][2];          // [kp][hb]
#pragma unroll
      for (int kp = 0; kp < 2; ++kp)
#pragma unroll
        for (int hb = 0; hb < 2; ++hb)
          Af[kp][hb] = *(const short8v*)(WtF +
              ((size_t)(((kj * 2 + kp) * 2 + hb) * 64 + lane)) * 8);

      // ---- per C2 tile: in-register transpose -> stage3 B -> 4 MFMA
#pragma unroll
      for (int ms = 0; ms < 2; ++ms) {
#pragma unroll
        for (int ds = 0; ds < 2; ++ds) {
          uint P[8], Xc[8];
#pragma unroll
          for (int q = 0; q < 8; ++q)
            P[q] = packbf(acc2[ms][ds][2 * q], acc2[ms][ds][2 * q + 1]);
#pragma unroll
          for (int q = 0; q < 8; ++q) Xc[q] = (uint)__shfl_xor((int)P[q], 32);
          short8v Bf[2];
#pragma unroll
          for (int kp = 0; kp < 2; ++kp) {
            uint4 u;
            if (h5 == 0) {
              u.x = P[4 * kp];      u.y = P[4 * kp + 1];
              u.z = Xc[4 * kp];     u.w = Xc[4 * kp + 1];
            } else {
              u.x = Xc[4 * kp + 2]; u.y = Xc[4 * kp + 3];
              u.z = P[4 * kp + 2];  u.w = P[4 * kp + 3];
            }
            Bf[kp] = *(short8v*)&u;
          }
#pragma unroll
          for (int hb = 0; hb < 2; ++hb) {
#pragma unroll
            for (int kp = 0; kp < 2; ++kp)
              acc3[ms][ds][hb] = __builtin_amdgcn_mfma_f32_32x32x16_bf16(
                  Af[kp][hb], Bf[kp], acc3[ms][ds][hb], 0, 0, 0);
          }
          // zero acc2 for next (k,j)
#pragma unroll
          for (int q = 0; q < 16; ++q) acc2[ms][ds][q] = 0.f;
        }
      }
    }
  }

  // ---- epilogue: 2 passes of 2 m each; stage fp32 in swizzled LDS, then
  //      fully-coalesced stores with bias+ReLU.
  float4* EP = (float4*)base;    // [ml 2][d 128][hgran 16] float4 = 64 KB
#pragma unroll
  for (int mlp = 0; mlp < 2; ++mlp) {
    __syncthreads();             // LDS free / prior pass consumed
    if ((w >> 1) == mlp) {
#pragma unroll
      for (int ms = 0; ms < 2; ++ms) {
#pragma unroll
        for (int ds = 0; ds < 2; ++ds) {
          const int d = wd + ds * 32 + l5;
#pragma unroll
          for (int hb = 0; hb < 2; ++hb) {
#pragma unroll
            for (int s = 0; s < 4; ++s) {
              const int hg = 2 * s + h5 + 8 * hb;   // float4 granule of h
              float4 v;
              v.x = acc3[ms][ds][hb][4 * s + 0];
              v.y = acc3[ms][ds][hb][4 * s + 1];
              v.z = acc3[ms][ds][hb][4 * s + 2];
              v.w = acc3[ms][ds][hb][4 * s + 3];
              EP[(ms * 128 + d) * 16 + (hg ^ (d & 15))] = v;
            }
          }
        }
      }
    }
    __syncthreads();
    // coalesced store of 2 m rows (2 x 32 KB)
#pragma unroll
    for (int ii = 0; ii < 16; ++ii) {
      const int fi = tid + ii * 256;         // 0..4095 float4
      const int ml = fi >> 11;
      const int d  = (fi >> 4) & 127;
      const int hg = fi & 15;
      float4 v = EP[(ml * 128 + d) * 16 + (hg ^ (d & 15))];
      const float4 bb = *(const float4*)(bias + hg * 4);
      v.x = fmaxf(v.x + bb.x, 0.f);
      v.y = fmaxf(v.y + bb.y, 0.f);
      v.z = fmaxf(v.z + bb.z, 0.f);
      v.w = fmaxf(v.w + bb.w, 0.f);
      const int m = mp * 4 + mlp * 2 + ml;
      float* ob = out + (((size_t)b * NN + m) * NN + d0 + d) * NH;
      *(float4*)(ob + hg * 4) = v;
    }
  }
}

extern "C" void kernel_launch(void* const* d_in, const int* in_sizes, int n_in,
                              void* d_out, int out_size, void* d_ws, size_t ws_size,
                              hipStream_t stream) {
  (void)in_sizes; (void)n_in; (void)out_size; (void)ws_size;
  const float* X    = (const float*)d_in[0];
  const float* G    = (const float*)d_in[1];
  const float* W    = (const float*)d_in[2];
  const float* bias = (const float*)d_in[3];
  float* out = (float*)d_out;

  char* p = (char*)d_ws;
  ushort* Gt  = (ushort*)p;  p += (size_t)3 * NN * NN * 2;  // 384 KB
  ushort* WtF = (ushort*)p;  p += (size_t)64 * 1024;        // 36.9 KB (padded)
  ushort* Xt  = (ushort*)p;  p += (size_t)NB * SL * 2;      // 33.5 MB
  ushort* T1  = (ushort*)p;                                 // 100.7 MB

  prep_g<<<dim3(8, 8, 3), 256, 0, stream>>>(G, Gt);
  prep_wf<<<dim3(1), 256, 0, stream>>>(W, WtF);
  prep_x<<<dim3(256, 8, NB), 256, 0, stream>>>(X, Xt);

  // Stage 1 for all (b,k): z = b*3+k ; A = Gt[k], Bt = Xt[b], C = T1[z]
  gemm_bt<<<dim3(NQ / 128, NN / 128, 24), 256, 0, stream>>>(
      Gt, Xt, T1, NQ, NN, (size_t)NN * NN, SL, SL);

  // Fused stage 2+3 (1024 logical blocks, XCD-swizzled)
  fused_s23<<<dim3(1024), 256, 0, stream>>>(T1, Gt, WtF, bias, out);
}